// Round 15
// baseline (126.197 us; speedup 1.0000x reference)
//
#include <hip/hip_runtime.h>
#include <hip/hip_bf16.h>
#include <hip/hip_fp16.h>
#include <math.h>

#define BS 16
#define LQ 300
#define NH 8
#define HD 32
#define SP 16       // NUM_LEVELS * NUM_POINTS
#define ED 256
#define LV 8500
#define NB_BLK 300               // kB tiles: 4800 queries / 16
#define CHUNKS 8                 // px chunks per bn
#define CHPX 1088                // ceil(8500/8) rounded to 64: 1088*7+884
#define NTR_BLK (128 * CHUNKS)   // 1024

static __device__ __forceinline__ int imin(int a, int b) { return a < b ? a : b; }
static __device__ __forceinline__ int imax(int a, int b) { return a > b ? a : b; }

static __device__ __forceinline__ unsigned f2bf(float x) {
    unsigned u = __float_as_uint(x);
    return (u + 0x7fffu + ((u >> 16) & 1u)) >> 16;   // RNE
}

static __device__ __forceinline__ unsigned pk2h(float a, float b) {
    __half ha = __float2half_rn(a), hb = __float2half_rn(b);
    unsigned short ua = *reinterpret_cast<unsigned short*>(&ha);
    unsigned short ub = *reinterpret_cast<unsigned short*>(&hb);
    return (unsigned)ua | ((unsigned)ub << 16);
}

static __device__ __forceinline__ float2 up2h(unsigned u) {
    unsigned short ua = (unsigned short)(u & 0xffffu);
    unsigned short ub = (unsigned short)(u >> 16);
    __half ha = *reinterpret_cast<__half*>(&ua);
    __half hb = *reinterpret_cast<__half*>(&ub);
    return make_float2(__half2float(ha), __half2float(hb));
}

// ---------------------------------------------------------------------------
// kF: fused {kB: logits+softmax+locations -> la (16B records)} and
// {transpose v9: barrier-free, LDS-free wave-local transpose}.
// Wave w owns channels w*8..w*8+7. Lane l reads px l of each of its 8 rows
// (8 scalar dword loads, 256B/instr coalesced) -> lane holds the full
// 8-channel column of its pixel IN REGISTERS -> cvt/pack -> one 16-B store
// at record offset w*16. The 4 waves of a block fill the 64-B records of a
// 4KB region within ~us; same-CU L2 merges. No __syncthreads anywhere in
// the transpose -> every wave streams continuously (m13 copy structure).
// ---------------------------------------------------------------------------
__global__ __launch_bounds__(256) void kF(const float* __restrict__ query,
                                          const float* __restrict__ refp,
                                          const float* __restrict__ Woff,
                                          const float* __restrict__ boff,
                                          const float* __restrict__ Wattn,
                                          const float* __restrict__ battn,
                                          const float* __restrict__ nps,
                                          unsigned* __restrict__ la,
                                          const float* __restrict__ v,
                                          __hip_bfloat16* __restrict__ vt,
                                          int nb) {
    __shared__ float s[16 * 384];          // 24 KB, kB path only
    const int tid = threadIdx.x;

    if ((int)blockIdx.x >= nb) {
        // -------- transpose path: bn x 1088-px chunk, 4 waves x 8 ch --------
        const int t     = blockIdx.x - nb;     // 0..1023
        const int bn    = t >> 3;
        const int chunk = t & 7;
        const int px0   = chunk * CHPX;
        const int pxe   = imin(px0 + CHPX, LV);
        const int w     = tid >> 6;            // wave 0..3: channels w*8..+7
        const int l     = tid & 63;

        const float* src = v + ((size_t)bn * HD + w * 8) * LV;
        char* dst = (char*)vt + (size_t)bn * LV * (HD * 2) + w * 16;

#pragma unroll 2
        for (int p = px0 + l; p < pxe; p += 64) {
            float r[8];
#pragma unroll
            for (int k = 0; k < 8; ++k) r[k] = src[(size_t)k * LV + p];
            unsigned pk[4];
#pragma unroll
            for (int k = 0; k < 4; ++k)
                pk[k] = f2bf(r[2 * k]) | (f2bf(r[2 * k + 1]) << 16);
            *reinterpret_cast<uint4*>(dst + (size_t)p * 64) =
                make_uint4(pk[0], pk[1], pk[2], pk[3]);
        }
        return;
    }

    // ---------------- kB path: 16 queries, 2 per thread ----------------
    float* qbuf = s;        // 16*256, dead after k-loop
    float* lbuf = s;        // 16*384 = 24 KB, written after sync
    const int gq0 = blockIdx.x * 16;

    const float* qsrc = query + (size_t)gq0 * ED;
#pragma unroll
    for (int i = 0; i < 16; ++i) qbuf[tid + 256 * i] = qsrc[tid + 256 * i];
    __syncthreads();

    const int qi = tid >> 5;        // 0..7
    const int cl = tid & 31;
    const float* qa = qbuf + qi * ED;
    const float* qb = qbuf + (qi + 8) * ED;

    float a0[4] = {0,0,0,0}, a1[4] = {0,0,0,0}, a2[4] = {0,0,0,0};
    float c0[4] = {0,0,0,0}, c1[4] = {0,0,0,0}, c2[4] = {0,0,0,0};
    const float4* w0 = (const float4*)(Woff + cl * 4);
    const float4* w1 = (const float4*)(Woff + 128 + cl * 4);
    const float4* w2 = (const float4*)(Wattn + cl * 4);
#pragma unroll 4
    for (int k = 0; k < ED; ++k) {
        float va = qa[k], vb = qb[k];
        float4 x0 = w0[k * 64];
        float4 x1 = w1[k * 64];
        float4 x2 = w2[k * 32];
        a0[0] += va * x0.x; a0[1] += va * x0.y; a0[2] += va * x0.z; a0[3] += va * x0.w;
        a1[0] += va * x1.x; a1[1] += va * x1.y; a1[2] += va * x1.z; a1[3] += va * x1.w;
        a2[0] += va * x2.x; a2[1] += va * x2.y; a2[2] += va * x2.z; a2[3] += va * x2.w;
        c0[0] += vb * x0.x; c0[1] += vb * x0.y; c0[2] += vb * x0.z; c0[3] += vb * x0.w;
        c1[0] += vb * x1.x; c1[1] += vb * x1.y; c1[2] += vb * x1.z; c1[3] += vb * x1.w;
        c2[0] += vb * x2.x; c2[1] += vb * x2.y; c2[2] += vb * x2.z; c2[3] += vb * x2.w;
    }
    __syncthreads();   // qbuf dead from here; lbuf may overwrite it
    {
        float* ra = lbuf + qi * 384;
        float* rb = lbuf + (qi + 8) * 384;
#pragma unroll
        for (int u = 0; u < 4; ++u) {
            float bo0 = boff[cl * 4 + u];
            float bo1 = boff[128 + cl * 4 + u];
            float ba  = battn[cl * 4 + u];
            ra[cl * 4 + u]       = a0[u] + bo0;
            ra[128 + cl * 4 + u] = a1[u] + bo1;
            ra[256 + cl * 4 + u] = a2[u] + ba;
            rb[cl * 4 + u]       = c0[u] + bo0;
            rb[128 + cl * 4 + u] = c1[u] + bo1;
            rb[256 + cl * 4 + u] = c2[u] + ba;
        }
    }
    __syncthreads();

    // ---- softmax + locations; quad (pg = tid&3) reduction via shuffles ----
#pragma unroll
    for (int it = 0; it < 2; ++it) {
        const int slot = it * 256 + tid;
        const int qi2 = slot >> 5;          // 0..15
        const int h2  = (slot >> 2) & 7;
        const int pg  = slot & 3;           // level; quad-aligned in the wave
        const float* lr = lbuf + qi2 * 384;

        float l[4];
#pragma unroll
        for (int i = 0; i < 4; ++i) l[i] = lr[256 + h2 * 16 + pg * 4 + i];
        float m = fmaxf(fmaxf(l[0], l[1]), fmaxf(l[2], l[3]));
        m = fmaxf(m, __shfl_xor(m, 1));
        m = fmaxf(m, __shfl_xor(m, 2));
        float e[4];
        float ps = 0.f;
#pragma unroll
        for (int i = 0; i < 4; ++i) { e[i] = expf(l[i] - m); ps += e[i]; }
        ps += __shfl_xor(ps, 1);
        ps += __shfl_xor(ps, 2);
        float inv = 1.f / ps;

        const int gq = gq0 + qi2;
        const int b  = gq / LQ;
        const int q  = gq - b * LQ;
        const float* rp = refp + (size_t)gq * 4;
        float cx = rp[0], cy = rp[1], rw = rp[2], rh = rp[3];

        const int Wl = 80 >> pg;
        const int base = (25600 - (25600 >> (2 * pg))) / 3;   // 0,6400,8000,8400
        const float fw = (float)Wl;

        // la layout: [b][h][q][p] 16B records
        unsigned* dst = la + ((((size_t)b * NH + h2) * LQ + q) * SP + pg * 4) * 4;
#pragma unroll
        for (int i = 0; i < 4; ++i) {
            int p = pg * 4 + i;
            float ox = lr[h2 * 32 + p * 2 + 0];
            float oy = lr[h2 * 32 + p * 2 + 1];
            float sc = nps[p] * 0.5f;
            float locx = cx + ox * sc * rw;
            float locy = cy + oy * sc * rh;
            float x = locx * fw - 0.5f;
            float y = locy * fw - 0.5f;
            float aw = e[i] * inv;

            float x0f = floorf(x), y0f = floorf(y);
            float fx = x - x0f, fy = y - y0f;
            int ix0 = (int)x0f, iy0 = (int)y0f;
            int ix1 = ix0 + 1, iy1 = iy0 + 1;
            bool vx0 = (ix0 >= 0) && (ix0 < Wl);
            bool vx1 = (ix1 >= 0) && (ix1 < Wl);
            bool vy0 = (iy0 >= 0) && (iy0 < Wl);
            bool vy1 = (iy1 >= 0) && (iy1 < Wl);
            int cx0 = imin(imax(ix0, 0), Wl - 1);
            int cx1 = imin(imax(ix1, 0), Wl - 1);
            int cy0 = imin(imax(iy0, 0), Wl - 1);
            int cy1 = imin(imax(iy1, 0), Wl - 1);
            float w00 = aw * (1.f - fx) * (1.f - fy) * ((vx0 && vy0) ? 1.f : 0.f);
            float w10 = aw * fx * (1.f - fy) * ((vx1 && vy0) ? 1.f : 0.f);
            float w01 = aw * (1.f - fx) * fy * ((vx0 && vy1) ? 1.f : 0.f);
            float w11 = aw * fx * fy * ((vx1 && vy1) ? 1.f : 0.f);
            unsigned i00 = (unsigned)(base + cy0 * Wl + cx0);
            unsigned i10 = (unsigned)(base + cy0 * Wl + cx1);
            unsigned i01 = (unsigned)(base + cy1 * Wl + cx0);
            unsigned i11 = (unsigned)(base + cy1 * Wl + cx1);

            *reinterpret_cast<uint4*>(dst + i * 4) =
                make_uint4(pk2h(w00, w10), pk2h(w01, w11),
                           i00 | (i10 << 16), i01 | (i11 << 16));
        }
    }
}

// ---------------------------------------------------------------------------
// kC4: gather + weighted sum from bf16 value_t (BN, LV, HD). No LDS: the la
// record is quad-broadcast from L1 (4 channel-lanes share it). Block 128 thr
// = 32 queries x 4 lanes; lane owns 8 channels (16 B uint4 gathers). 1280
// blocks (10 q-tiles x 128 bh), XCD-chunked swizzle (1280 = 8*160).
// ---------------------------------------------------------------------------
__global__ __launch_bounds__(128) void kC4(const __hip_bfloat16* __restrict__ vt,
                                           const unsigned* __restrict__ la,
                                           float* __restrict__ out) {
    const int bid = blockIdx.x;
    const int logical = (bid & 7) * 160 + (bid >> 3);
    const int bh = logical / 10;
    const int qt = logical - bh * 10;
    const int b = bh >> 3;
    const int h = bh & 7;

    const int tid = threadIdx.x;
    const int qs = tid >> 2;            // 0..31
    const int l4 = tid & 3;             // lane's 8-channel group
    const int q = qt * 32 + qs;
    if (q >= LQ) return;

    const unsigned* lq = la + (((size_t)bh * LQ + q) * SP) * 4;
    const char* vb = (const char*)vt + (size_t)bh * LV * (HD * 2) + l4 * 16;

    float acc[8] = {0.f, 0.f, 0.f, 0.f, 0.f, 0.f, 0.f, 0.f};

#pragma unroll 2
    for (int p = 0; p < SP; p += 2) {
        uint4 rec0 = *reinterpret_cast<const uint4*>(lq + p * 4);
        uint4 rec1 = *reinterpret_cast<const uint4*>(lq + p * 4 + 4);
        uint4 r0 = *reinterpret_cast<const uint4*>(vb + (size_t)(rec0.z & 0xffffu) * 64);
        uint4 r1 = *reinterpret_cast<const uint4*>(vb + (size_t)(rec0.z >> 16) * 64);
        uint4 r2 = *reinterpret_cast<const uint4*>(vb + (size_t)(rec0.w & 0xffffu) * 64);
        uint4 r3 = *reinterpret_cast<const uint4*>(vb + (size_t)(rec0.w >> 16) * 64);
        uint4 r4 = *reinterpret_cast<const uint4*>(vb + (size_t)(rec1.z & 0xffffu) * 64);
        uint4 r5 = *reinterpret_cast<const uint4*>(vb + (size_t)(rec1.z >> 16) * 64);
        uint4 r6 = *reinterpret_cast<const uint4*>(vb + (size_t)(rec1.w & 0xffffu) * 64);
        uint4 r7 = *reinterpret_cast<const uint4*>(vb + (size_t)(rec1.w >> 16) * 64);
        float2 wA0 = up2h(rec0.x), wB0 = up2h(rec0.y);
        float2 wA1 = up2h(rec1.x), wB1 = up2h(rec1.y);
#define FMA8(W, R)                                                             \
        {                                                                      \
            union { unsigned u; float f; } _t;                                 \
            _t.u = (R).x << 16;         acc[0] = fmaf((W), _t.f, acc[0]);      \
            _t.u = (R).x & 0xffff0000u; acc[1] = fmaf((W), _t.f, acc[1]);      \
            _t.u = (R).y << 16;         acc[2] = fmaf((W), _t.f, acc[2]);      \
            _t.u = (R).y & 0xffff0000u; acc[3] = fmaf((W), _t.f, acc[3]);      \
            _t.u = (R).z << 16;         acc[4] = fmaf((W), _t.f, acc[4]);      \
            _t.u = (R).z & 0xffff0000u; acc[5] = fmaf((W), _t.f, acc[5]);      \
            _t.u = (R).w << 16;         acc[6] = fmaf((W), _t.f, acc[6]);      \
            _t.u = (R).w & 0xffff0000u; acc[7] = fmaf((W), _t.f, acc[7]);      \
        }
        FMA8(wA0.x, r0) FMA8(wA0.y, r1) FMA8(wB0.x, r2) FMA8(wB0.y, r3)
        FMA8(wA1.x, r4) FMA8(wA1.y, r5) FMA8(wB1.x, r6) FMA8(wB1.y, r7)
#undef FMA8
    }
    float* op = out + ((size_t)b * LQ + q) * ED + h * HD + l4 * 8;
    *reinterpret_cast<float4*>(op)     = make_float4(acc[0], acc[1], acc[2], acc[3]);
    *reinterpret_cast<float4*>(op + 4) = make_float4(acc[4], acc[5], acc[6], acc[7]);
}

// ---------------------------------------------------------------------------
// Fallback (ws too small): gather from original f32 layout.
// ---------------------------------------------------------------------------
__global__ __launch_bounds__(320) void kCfb(const float* __restrict__ val,
                                            const unsigned* __restrict__ la,
                                            float* __restrict__ out) {
    __shared__ __align__(16) unsigned sla[10 * SP * 4];
    int bid = blockIdx.x;
    int logical = (bid & 7) * 480 + (bid >> 3);
    int bh = logical / 30;
    int qt = logical - bh * 30;
    int b = bh >> 3;
    int h = bh & 7;
    const int tid = threadIdx.x;
    const unsigned* lsrc = la + (((size_t)bh * LQ + qt * 10) * SP) * 4;
    for (int i = tid; i < 640; i += 320) sla[i] = lsrc[i];
    __syncthreads();
    const int qs = tid >> 5;
    const int c  = tid & 31;
    const float* vb = val + ((size_t)bh * HD + c) * LV;
    float acc = 0.f;
    const unsigned* lq = sla + qs * (SP * 4);
#pragma unroll
    for (int p = 0; p < SP; ++p) {
        uint4 rec = *reinterpret_cast<const uint4*>(lq + p * 4);
        float2 wA = up2h(rec.x), wB = up2h(rec.y);
        acc += wA.x * vb[rec.z & 0xffffu];
        acc += wA.y * vb[rec.z >> 16];
        acc += wB.x * vb[rec.w & 0xffffu];
        acc += wB.y * vb[rec.w >> 16];
    }
    int q = qt * 10 + qs;
    out[((size_t)b * LQ + q) * ED + h * HD + c] = acc;
}

// ---------------------------------------------------------------------------
extern "C" void kernel_launch(void* const* d_in, const int* in_sizes, int n_in,
                              void* d_out, int out_size, void* d_ws, size_t ws_size,
                              hipStream_t stream) {
    const float* query = (const float*)d_in[0];
    const float* refp  = (const float*)d_in[1];
    const float* value = (const float*)d_in[2];
    // d_in[3]: value_spatial_shapes (int64) — fixed constants, hard-coded.
    const float* Woff  = (const float*)d_in[4];
    const float* boff  = (const float*)d_in[5];
    const float* Wattn = (const float*)d_in[6];
    const float* battn = (const float*)d_in[7];
    const float* nps   = (const float*)d_in[8];
    float* out = (float*)d_out;

    const size_t la_bytes = (size_t)BS * NH * LQ * SP * 16;                     // ~9.8 MB
    const size_t vt_bytes = (size_t)BS * NH * LV * HD * sizeof(__hip_bfloat16); // ~69.6 MB
    unsigned* la = (unsigned*)d_ws;
    __hip_bfloat16* vt = (__hip_bfloat16*)((char*)d_ws + la_bytes);
    const bool use_tr = ws_size >= la_bytes + vt_bytes;

    if (use_tr) {
        kF<<<dim3(NB_BLK + NTR_BLK), 256, 0, stream>>>(query, refp, Woff, boff,
                                                       Wattn, battn, nps, la,
                                                       value, vt, NB_BLK);
        kC4<<<dim3(1280), 128, 0, stream>>>(vt, la, out);
    } else {
        kF<<<dim3(NB_BLK), 256, 0, stream>>>(query, refp, Woff, boff,
                                             Wattn, battn, nps, la,
                                             value, (__hip_bfloat16*)nullptr, NB_BLK);
        kCfb<<<dim3(3840), 320, 0, stream>>>(value, la, out);
    }
}

// Round 16
// 70.084 us; speedup vs baseline: 1.8007x; 1.8007x over previous
//
#include <hip/hip_runtime.h>
#include <hip/hip_bf16.h>
#include <hip/hip_fp16.h>
#include <math.h>

#define BS 16
#define LQ 300
#define NH 8
#define HD 32
#define SP 16       // NUM_LEVELS * NUM_POINTS
#define ED 256
#define LV 8500
#define NB_BLK 300               // kB tiles: 4800 queries / 16
#define PXT 256                  // transpose pixel tile
#define TR_PER_BN 34             // ceil(8500 / 256)
#define NTILES (TR_PER_BN * 128) // 4352
#define TPB 8                    // tiles per persistent transpose block
#define NTRB (NTILES / TPB)      // 544

static __device__ __forceinline__ int imin(int a, int b) { return a < b ? a : b; }
static __device__ __forceinline__ int imax(int a, int b) { return a > b ? a : b; }

static __device__ __forceinline__ unsigned f2bf(float x) {
    unsigned u = __float_as_uint(x);
    return (u + 0x7fffu + ((u >> 16) & 1u)) >> 16;   // RNE
}

static __device__ __forceinline__ unsigned pk2h(float a, float b) {
    __half ha = __float2half_rn(a), hb = __float2half_rn(b);
    unsigned short ua = *reinterpret_cast<unsigned short*>(&ha);
    unsigned short ub = *reinterpret_cast<unsigned short*>(&hb);
    return (unsigned)ua | ((unsigned)ub << 16);
}

static __device__ __forceinline__ float2 up2h(unsigned u) {
    unsigned short ua = (unsigned short)(u & 0xffffu);
    unsigned short ub = (unsigned short)(u >> 16);
    __half ha = *reinterpret_cast<__half*>(&ua);
    __half hb = *reinterpret_cast<__half*>(&ub);
    return make_float2(__half2float(ha), __half2float(hb));
}

// HBM -> LDS direct DMA, 16 B per lane (global_load_lds_dwordx4).
static __device__ __forceinline__ void gload16(const float* g, float* l) {
    __builtin_amdgcn_global_load_lds(
        (const __attribute__((address_space(1))) void*)g,
        (__attribute__((address_space(3))) void*)l, 16, 0, 0);
}

// ---------------------------------------------------------------------------
// kF: fused {kB: logits+softmax+locations -> la (16B records)} and
// {transpose v8: persistent blocks (TPB=8 tiles), double-buffered LDS,
// global_load_lds DMA + COUNTED vmcnt(8) so the next tile's 8 DMAs stay in
// flight across the barrier}. Best-known configuration (R14, 70.3 us).
// ---------------------------------------------------------------------------
__global__ __launch_bounds__(256) void kF(const float* __restrict__ query,
                                          const float* __restrict__ refp,
                                          const float* __restrict__ Woff,
                                          const float* __restrict__ boff,
                                          const float* __restrict__ Wattn,
                                          const float* __restrict__ battn,
                                          const float* __restrict__ nps,
                                          unsigned* __restrict__ la,
                                          const float* __restrict__ v,
                                          __hip_bfloat16* __restrict__ vt,
                                          int nb) {
    __shared__ float s[2][32 * 256];       // 64 KB: 2 transpose buffers; kB
    const int tid = threadIdx.x;           // uses s[0] (24 KB)

    if ((int)blockIdx.x >= nb) {
        // -------- transpose path: TPB tiles of 32 ch x 256 px, pipelined ----
        const int blk = blockIdx.x - nb;   // 0..NTRB-1
        const int t0  = blk * TPB;
        const int w   = tid >> 6;          // wave 0..3
        const int l   = tid & 63;
        const int p2  = tid >> 2;
        const int q   = tid & 3;

        auto issue = [&](int t, float* buf) {
            int bn  = t / TR_PER_BN;
            int ti  = t - bn * TR_PER_BN;
            int px0 = ti * PXT;
            int nlv = imin(PXT, LV - px0);
            if (l * 4 < nlv) {
                const float* src = v + ((size_t)bn * HD + w * 8) * LV + px0 + l * 4;
#pragma unroll
                for (int k = 0; k < 8; ++k)
                    gload16(src + (size_t)k * LV, buf + (w * 8 + k) * 256);
            }
        };

        issue(t0, s[0]);                   // prologue: 8 outstanding

#pragma unroll
        for (int tt = 0; tt < TPB; ++tt) {
            float* cur = s[tt & 1];
            float* nxt = s[(tt & 1) ^ 1];
            if (tt + 1 < TPB) {
                issue(t0 + tt + 1, nxt);                         // 16 outstanding
                asm volatile("s_waitcnt vmcnt(8)" ::: "memory"); // tile tt landed
            } else {
                asm volatile("s_waitcnt vmcnt(0)" ::: "memory");
            }
            __builtin_amdgcn_s_barrier();          // all waves: tile tt in LDS
            __builtin_amdgcn_sched_barrier(0);

            // pack/store tile tt from cur
            const int t  = t0 + tt;
            const int bn = t / TR_PER_BN;
            const int ti = t - bn * TR_PER_BN;
            const int px0 = ti * PXT;
            const int nlv = imin(PXT, LV - px0);
            char* dst0 = (char*)vt + ((size_t)bn * LV + px0) * (HD * 2) + q * 16;
#pragma unroll
            for (int j = 0; j < 4; ++j) {
                int p = p2 + 64 * j;
                if (p < nlv) {
                    unsigned pk[4];
#pragma unroll
                    for (int i = 0; i < 4; ++i) {
                        float f0 = cur[(8 * q + 2 * i) * 256 + p];
                        float f1 = cur[(8 * q + 2 * i + 1) * 256 + p];
                        pk[i] = f2bf(f0) | (f2bf(f1) << 16);
                    }
                    *reinterpret_cast<uint4*>(dst0 + (size_t)p * 64) =
                        make_uint4(pk[0], pk[1], pk[2], pk[3]);
                }
            }
            __builtin_amdgcn_s_barrier();   // pack done before next overwrite
        }
        return;
    }

    // ---------------- kB path: 16 queries, 2 per thread ----------------
    float* qbuf = s[0];     // 16*256, dead after k-loop
    float* lbuf = s[0];     // 16*384 = 24 KB, written after sync
    const int gq0 = blockIdx.x * 16;

    const float* qsrc = query + (size_t)gq0 * ED;
#pragma unroll
    for (int i = 0; i < 16; ++i) qbuf[tid + 256 * i] = qsrc[tid + 256 * i];
    __syncthreads();

    const int qi = tid >> 5;        // 0..7
    const int cl = tid & 31;
    const float* qa = qbuf + qi * ED;
    const float* qb = qbuf + (qi + 8) * ED;

    float a0[4] = {0,0,0,0}, a1[4] = {0,0,0,0}, a2[4] = {0,0,0,0};
    float c0[4] = {0,0,0,0}, c1[4] = {0,0,0,0}, c2[4] = {0,0,0,0};
    const float4* w0 = (const float4*)(Woff + cl * 4);
    const float4* w1 = (const float4*)(Woff + 128 + cl * 4);
    const float4* w2 = (const float4*)(Wattn + cl * 4);
#pragma unroll 4
    for (int k = 0; k < ED; ++k) {
        float va = qa[k], vb = qb[k];
        float4 x0 = w0[k * 64];
        float4 x1 = w1[k * 64];
        float4 x2 = w2[k * 32];
        a0[0] += va * x0.x; a0[1] += va * x0.y; a0[2] += va * x0.z; a0[3] += va * x0.w;
        a1[0] += va * x1.x; a1[1] += va * x1.y; a1[2] += va * x1.z; a1[3] += va * x1.w;
        a2[0] += va * x2.x; a2[1] += va * x2.y; a2[2] += va * x2.z; a2[3] += va * x2.w;
        c0[0] += vb * x0.x; c0[1] += vb * x0.y; c0[2] += vb * x0.z; c0[3] += vb * x0.w;
        c1[0] += vb * x1.x; c1[1] += vb * x1.y; c1[2] += vb * x1.z; c1[3] += vb * x1.w;
        c2[0] += vb * x2.x; c2[1] += vb * x2.y; c2[2] += vb * x2.z; c2[3] += vb * x2.w;
    }
    __syncthreads();   // qbuf dead from here; lbuf may overwrite it
    {
        float* ra = lbuf + qi * 384;
        float* rb = lbuf + (qi + 8) * 384;
#pragma unroll
        for (int u = 0; u < 4; ++u) {
            float bo0 = boff[cl * 4 + u];
            float bo1 = boff[128 + cl * 4 + u];
            float ba  = battn[cl * 4 + u];
            ra[cl * 4 + u]       = a0[u] + bo0;
            ra[128 + cl * 4 + u] = a1[u] + bo1;
            ra[256 + cl * 4 + u] = a2[u] + ba;
            rb[cl * 4 + u]       = c0[u] + bo0;
            rb[128 + cl * 4 + u] = c1[u] + bo1;
            rb[256 + cl * 4 + u] = c2[u] + ba;
        }
    }
    __syncthreads();

    // ---- softmax + locations; quad (pg = tid&3) reduction via shuffles ----
#pragma unroll
    for (int it = 0; it < 2; ++it) {
        const int slot = it * 256 + tid;
        const int qi2 = slot >> 5;          // 0..15
        const int h2  = (slot >> 2) & 7;
        const int pg  = slot & 3;           // level; quad-aligned in the wave
        const float* lr = lbuf + qi2 * 384;

        float l[4];
#pragma unroll
        for (int i = 0; i < 4; ++i) l[i] = lr[256 + h2 * 16 + pg * 4 + i];
        float m = fmaxf(fmaxf(l[0], l[1]), fmaxf(l[2], l[3]));
        m = fmaxf(m, __shfl_xor(m, 1));
        m = fmaxf(m, __shfl_xor(m, 2));
        float e[4];
        float ps = 0.f;
#pragma unroll
        for (int i = 0; i < 4; ++i) { e[i] = expf(l[i] - m); ps += e[i]; }
        ps += __shfl_xor(ps, 1);
        ps += __shfl_xor(ps, 2);
        float inv = 1.f / ps;

        const int gq = gq0 + qi2;
        const int b  = gq / LQ;
        const int q  = gq - b * LQ;
        const float* rp = refp + (size_t)gq * 4;
        float cx = rp[0], cy = rp[1], rw = rp[2], rh = rp[3];

        const int Wl = 80 >> pg;
        const int base = (25600 - (25600 >> (2 * pg))) / 3;   // 0,6400,8000,8400
        const float fw = (float)Wl;

        // la layout: [b][h][q][p] 16B records
        unsigned* dst = la + ((((size_t)b * NH + h2) * LQ + q) * SP + pg * 4) * 4;
#pragma unroll
        for (int i = 0; i < 4; ++i) {
            int p = pg * 4 + i;
            float ox = lr[h2 * 32 + p * 2 + 0];
            float oy = lr[h2 * 32 + p * 2 + 1];
            float sc = nps[p] * 0.5f;
            float locx = cx + ox * sc * rw;
            float locy = cy + oy * sc * rh;
            float x = locx * fw - 0.5f;
            float y = locy * fw - 0.5f;
            float aw = e[i] * inv;

            float x0f = floorf(x), y0f = floorf(y);
            float fx = x - x0f, fy = y - y0f;
            int ix0 = (int)x0f, iy0 = (int)y0f;
            int ix1 = ix0 + 1, iy1 = iy0 + 1;
            bool vx0 = (ix0 >= 0) && (ix0 < Wl);
            bool vx1 = (ix1 >= 0) && (ix1 < Wl);
            bool vy0 = (iy0 >= 0) && (iy0 < Wl);
            bool vy1 = (iy1 >= 0) && (iy1 < Wl);
            int cx0 = imin(imax(ix0, 0), Wl - 1);
            int cx1 = imin(imax(ix1, 0), Wl - 1);
            int cy0 = imin(imax(iy0, 0), Wl - 1);
            int cy1 = imin(imax(iy1, 0), Wl - 1);
            float w00 = aw * (1.f - fx) * (1.f - fy) * ((vx0 && vy0) ? 1.f : 0.f);
            float w10 = aw * fx * (1.f - fy) * ((vx1 && vy0) ? 1.f : 0.f);
            float w01 = aw * (1.f - fx) * fy * ((vx0 && vy1) ? 1.f : 0.f);
            float w11 = aw * fx * fy * ((vx1 && vy1) ? 1.f : 0.f);
            unsigned i00 = (unsigned)(base + cy0 * Wl + cx0);
            unsigned i10 = (unsigned)(base + cy0 * Wl + cx1);
            unsigned i01 = (unsigned)(base + cy1 * Wl + cx0);
            unsigned i11 = (unsigned)(base + cy1 * Wl + cx1);

            *reinterpret_cast<uint4*>(dst + i * 4) =
                make_uint4(pk2h(w00, w10), pk2h(w01, w11),
                           i00 | (i10 << 16), i01 | (i11 << 16));
        }
    }
}

// ---------------------------------------------------------------------------
// kC4: gather + weighted sum from bf16 value_t (BN, LV, HD). No LDS: the la
// record is quad-broadcast from L1 (4 channel-lanes share it). Block 128 thr
// = 32 queries x 4 lanes; lane owns 8 channels (16 B uint4 gathers). 1280
// blocks (10 q-tiles x 128 bh), XCD-chunked swizzle (1280 = 8*160).
// ---------------------------------------------------------------------------
__global__ __launch_bounds__(128) void kC4(const __hip_bfloat16* __restrict__ vt,
                                           const unsigned* __restrict__ la,
                                           float* __restrict__ out) {
    const int bid = blockIdx.x;
    const int logical = (bid & 7) * 160 + (bid >> 3);
    const int bh = logical / 10;
    const int qt = logical - bh * 10;
    const int b = bh >> 3;
    const int h = bh & 7;

    const int tid = threadIdx.x;
    const int qs = tid >> 2;            // 0..31
    const int l4 = tid & 3;             // lane's 8-channel group
    const int q = qt * 32 + qs;
    if (q >= LQ) return;

    const unsigned* lq = la + (((size_t)bh * LQ + q) * SP) * 4;
    const char* vb = (const char*)vt + (size_t)bh * LV * (HD * 2) + l4 * 16;

    float acc[8] = {0.f, 0.f, 0.f, 0.f, 0.f, 0.f, 0.f, 0.f};

#pragma unroll 2
    for (int p = 0; p < SP; p += 2) {
        uint4 rec0 = *reinterpret_cast<const uint4*>(lq + p * 4);
        uint4 rec1 = *reinterpret_cast<const uint4*>(lq + p * 4 + 4);
        uint4 r0 = *reinterpret_cast<const uint4*>(vb + (size_t)(rec0.z & 0xffffu) * 64);
        uint4 r1 = *reinterpret_cast<const uint4*>(vb + (size_t)(rec0.z >> 16) * 64);
        uint4 r2 = *reinterpret_cast<const uint4*>(vb + (size_t)(rec0.w & 0xffffu) * 64);
        uint4 r3 = *reinterpret_cast<const uint4*>(vb + (size_t)(rec0.w >> 16) * 64);
        uint4 r4 = *reinterpret_cast<const uint4*>(vb + (size_t)(rec1.z & 0xffffu) * 64);
        uint4 r5 = *reinterpret_cast<const uint4*>(vb + (size_t)(rec1.z >> 16) * 64);
        uint4 r6 = *reinterpret_cast<const uint4*>(vb + (size_t)(rec1.w & 0xffffu) * 64);
        uint4 r7 = *reinterpret_cast<const uint4*>(vb + (size_t)(rec1.w >> 16) * 64);
        float2 wA0 = up2h(rec0.x), wB0 = up2h(rec0.y);
        float2 wA1 = up2h(rec1.x), wB1 = up2h(rec1.y);
#define FMA8(W, R)                                                             \
        {                                                                      \
            union { unsigned u; float f; } _t;                                 \
            _t.u = (R).x << 16;         acc[0] = fmaf((W), _t.f, acc[0]);      \
            _t.u = (R).x & 0xffff0000u; acc[1] = fmaf((W), _t.f, acc[1]);      \
            _t.u = (R).y << 16;         acc[2] = fmaf((W), _t.f, acc[2]);      \
            _t.u = (R).y & 0xffff0000u; acc[3] = fmaf((W), _t.f, acc[3]);      \
            _t.u = (R).z << 16;         acc[4] = fmaf((W), _t.f, acc[4]);      \
            _t.u = (R).z & 0xffff0000u; acc[5] = fmaf((W), _t.f, acc[5]);      \
            _t.u = (R).w << 16;         acc[6] = fmaf((W), _t.f, acc[6]);      \
            _t.u = (R).w & 0xffff0000u; acc[7] = fmaf((W), _t.f, acc[7]);      \
        }
        FMA8(wA0.x, r0) FMA8(wA0.y, r1) FMA8(wB0.x, r2) FMA8(wB0.y, r3)
        FMA8(wA1.x, r4) FMA8(wA1.y, r5) FMA8(wB1.x, r6) FMA8(wB1.y, r7)
#undef FMA8
    }
    float* op = out + ((size_t)b * LQ + q) * ED + h * HD + l4 * 8;
    *reinterpret_cast<float4*>(op)     = make_float4(acc[0], acc[1], acc[2], acc[3]);
    *reinterpret_cast<float4*>(op + 4) = make_float4(acc[4], acc[5], acc[6], acc[7]);
}

// ---------------------------------------------------------------------------
// Fallback (ws too small): gather from original f32 layout.
// ---------------------------------------------------------------------------
__global__ __launch_bounds__(320) void kCfb(const float* __restrict__ val,
                                            const unsigned* __restrict__ la,
                                            float* __restrict__ out) {
    __shared__ __align__(16) unsigned sla[10 * SP * 4];
    int bid = blockIdx.x;
    int logical = (bid & 7) * 480 + (bid >> 3);
    int bh = logical / 30;
    int qt = logical - bh * 30;
    int b = bh >> 3;
    int h = bh & 7;
    const int tid = threadIdx.x;
    const unsigned* lsrc = la + (((size_t)bh * LQ + qt * 10) * SP) * 4;
    for (int i = tid; i < 640; i += 320) sla[i] = lsrc[i];
    __syncthreads();
    const int qs = tid >> 5;
    const int c  = tid & 31;
    const float* vb = val + ((size_t)bh * HD + c) * LV;
    float acc = 0.f;
    const unsigned* lq = sla + qs * (SP * 4);
#pragma unroll
    for (int p = 0; p < SP; ++p) {
        uint4 rec = *reinterpret_cast<const uint4*>(lq + p * 4);
        float2 wA = up2h(rec.x), wB = up2h(rec.y);
        acc += wA.x * vb[rec.z & 0xffffu];
        acc += wA.y * vb[rec.z >> 16];
        acc += wB.x * vb[rec.w & 0xffffu];
        acc += wB.y * vb[rec.w >> 16];
    }
    int q = qt * 10 + qs;
    out[((size_t)b * LQ + q) * ED + h * HD + c] = acc;
}

// ---------------------------------------------------------------------------
extern "C" void kernel_launch(void* const* d_in, const int* in_sizes, int n_in,
                              void* d_out, int out_size, void* d_ws, size_t ws_size,
                              hipStream_t stream) {
    const float* query = (const float*)d_in[0];
    const float* refp  = (const float*)d_in[1];
    const float* value = (const float*)d_in[2];
    // d_in[3]: value_spatial_shapes (int64) — fixed constants, hard-coded.
    const float* Woff  = (const float*)d_in[4];
    const float* boff  = (const float*)d_in[5];
    const float* Wattn = (const float*)d_in[6];
    const float* battn = (const float*)d_in[7];
    const float* nps   = (const float*)d_in[8];
    float* out = (float*)d_out;

    const size_t la_bytes = (size_t)BS * NH * LQ * SP * 16;                     // ~9.8 MB
    const size_t vt_bytes = (size_t)BS * NH * LV * HD * sizeof(__hip_bfloat16); // ~69.6 MB
    unsigned* la = (unsigned*)d_ws;
    __hip_bfloat16* vt = (__hip_bfloat16*)((char*)d_ws + la_bytes);
    const bool use_tr = ws_size >= la_bytes + vt_bytes;

    if (use_tr) {
        kF<<<dim3(NB_BLK + NTRB), 256, 0, stream>>>(query, refp, Woff, boff,
                                                    Wattn, battn, nps, la,
                                                    value, vt, NB_BLK);
        kC4<<<dim3(1280), 128, 0, stream>>>(vt, la, out);
    } else {
        kF<<<dim3(NB_BLK), 256, 0, stream>>>(query, refp, Woff, boff,
                                             Wattn, battn, nps, la,
                                             value, (__hip_bfloat16*)nullptr, NB_BLK);
        kCfb<<<dim3(3840), 320, 0, stream>>>(value, la, out);
    }
}